// Round 1
// baseline (541.535 us; speedup 1.0000x reference)
//
#include <hip/hip_runtime.h>
#include <hip/hip_bf16.h>

// C=96 D=192 K=4 N=16 R=6 B=8 H=W=64 L=4096 ; chunked scan: 64 chunks x 64 steps

__device__ __forceinline__ float sigm(float x){ return 1.f/(1.f+__expf(-x)); }
__device__ __forceinline__ float softplus_(float x){ return (x>20.f)? x : __logf(1.f+__expf(x)); }

// involution mapping pixel<->scan index for direction k
__device__ __forceinline__ int perm_kl(int k, int v){
  if(k==0) return v;
  if(k==1) return ((v&63)<<6)|(v>>6);
  if(k==2) return 4095-v;
  int m = 4095-v; return ((m&63)<<6)|(m>>6);
}

// ---------------- K0: weight transposes ----------------
__global__ __launch_bounds__(256) void k0_prep(
    const float* __restrict__ ipw, const float* __restrict__ xpw,
    const float* __restrict__ dtw, const float* __restrict__ opw,
    const float* __restrict__ pmw,
    float* __restrict__ ipwT, float* __restrict__ xpwTp,
    float* __restrict__ dtwT, float* __restrict__ opwT,
    float* __restrict__ pmwT)
{
  int g = blockIdx.x*256 + threadIdx.x;
  if(g < 36864){                       // ipwT[c][n] = in_proj_w[n][c]  (96x384)
    int c = g/384, n = g%384;
    ipwT[g] = ipw[n*96 + c];
  } else if(g < 67584){                // xpwTp[d][k*40+c] (192x160, pad 38->40)
    int t = g - 36864; int d = t/160, n = t - d*160; int k = n/40, c = n - k*40;
    xpwTp[t] = (c < 38) ? xpw[(k*38 + c)*192 + d] : 0.f;
  } else if(g < 72192){                // dtwT[k][r][d] (4x6x192)
    int t = g - 67584; int kr = t/192, d = t - kr*192; int k = kr/6, r = kr - k*6;
    dtwT[t] = dtw[(k*192 + d)*6 + r];
  } else if(g < 90624){                // opwT[d][c] (192x96)
    int t = g - 72192; int d = t/96, c = t - d*96;
    opwT[t] = opw[c*192 + d];
  } else if(g < 164352){               // pmwT[n][cc] (384x192)
    int t = g - 90624; int n = t/192, c2 = t - n*192;
    pmwT[t] = pmw[c2*384 + n];
  }
}

// ---------------- K1: LN1 + in_proj GEMM (+resid transpose) ----------------
// grid (64 mtiles, 3 ntiles, 8 b), block 256.  BM=64 pos, BN=128, K=96.
#define XT_PAD 68
__global__ __launch_bounds__(256) void k1_ln_inproj(
    const float* __restrict__ x, const float* __restrict__ lnw, const float* __restrict__ lnb,
    const float* __restrict__ ipwT, float* __restrict__ xT,
    float* __restrict__ xp, float* __restrict__ z)
{
  __shared__ float xt[96*XT_PAD];
  __shared__ float lnw_s[96], lnb_s[96], mu_s[64], rs_s[64];
  int tid = threadIdx.x;
  int mt = blockIdx.x, nt = blockIdx.y, b = blockIdx.z;
  int g0 = mt*64;
  const float* xb = x + (size_t)b*96*4096 + g0;
  for(int idx=tid; idx<6144; idx+=256){
    int c = idx>>6, p = idx&63;
    xt[c*XT_PAD+p] = xb[c*4096 + p];
  }
  if(tid<96){ lnw_s[tid]=lnw[tid]; lnb_s[tid]=lnb[tid]; }
  __syncthreads();
  if(nt==0){  // residual: x transposed to (b,l,c)
    float* xTb = xT + ((size_t)(b*4096 + g0))*96;
    for(int idx=tid; idx<6144; idx+=256){
      int p = idx/96, c = idx - p*96;
      xTb[idx] = xt[c*XT_PAD+p];
    }
  }
  if(tid<64){
    float s=0.f,q=0.f;
    for(int c=0;c<96;c++){ float v=xt[c*XT_PAD+tid]; s+=v; q+=v*v; }
    float mu = s*(1.f/96.f);
    mu_s[tid]=mu; rs_s[tid]=rsqrtf(q*(1.f/96.f)-mu*mu+1e-5f);
  }
  __syncthreads();
  for(int idx=tid; idx<6144; idx+=256){
    int c = idx>>6, p = idx&63;
    int a = c*XT_PAD+p;
    xt[a] = (xt[a]-mu_s[p])*rs_s[p]*lnw_s[c]+lnb_s[c];
  }
  __syncthreads();
  int tm = tid>>5, tn = tid&31;
  float acc[8][4];
  #pragma unroll
  for(int i=0;i<8;i++){acc[i][0]=0.f;acc[i][1]=0.f;acc[i][2]=0.f;acc[i][3]=0.f;}
  const float* wbase = ipwT + nt*128 + tn*4;
  for(int kk=0;kk<96;kk++){
    float4 w4 = *(const float4*)(wbase + kk*384);
    float4 a0 = *(const float4*)&xt[kk*XT_PAD + tm*8];
    float4 a1 = *(const float4*)&xt[kk*XT_PAD + tm*8 + 4];
    float av[8]={a0.x,a0.y,a0.z,a0.w,a1.x,a1.y,a1.z,a1.w};
    #pragma unroll
    for(int i=0;i<8;i++){
      acc[i][0]=fmaf(av[i],w4.x,acc[i][0]);
      acc[i][1]=fmaf(av[i],w4.y,acc[i][1]);
      acc[i][2]=fmaf(av[i],w4.z,acc[i][2]);
      acc[i][3]=fmaf(av[i],w4.w,acc[i][3]);
    }
  }
  int n = nt*128 + tn*4;
  #pragma unroll
  for(int i=0;i<8;i++){
    size_t row = (size_t)(b*4096 + g0 + tm*8 + i);
    float4 v = make_float4(acc[i][0],acc[i][1],acc[i][2],acc[i][3]);
    if(n < 192) *(float4*)(xp + row*192 + n) = v;
    else        *(float4*)(z  + row*192 + (n-192)) = v;
  }
}

// ---------------- K2: depthwise 3x3 conv + bias + silu ----------------
__global__ __launch_bounds__(192) void k2_conv(
    const float* __restrict__ xp, const float* __restrict__ cw, const float* __restrict__ cb,
    float* __restrict__ xc)
{
  __shared__ float cw_s[1728];
  int tid = threadIdx.x;
  int p = blockIdx.x, b = blockIdx.y;
  for(int i=tid;i<1728;i+=192) cw_s[i]=cw[i];
  __syncthreads();
  int h = p>>6, w = p&63;
  const float* base = xp + (size_t)b*4096*192 + tid;
  float acc = cb[tid];
  #pragma unroll
  for(int ky=0;ky<3;ky++){
    int hh = h+ky-1;
    if(hh<0||hh>63) continue;
    #pragma unroll
    for(int kx=0;kx<3;kx++){
      int ww = w+kx-1;
      if(ww<0||ww>63) continue;
      acc = fmaf(base[(hh*64+ww)*192], cw_s[tid*9+ky*3+kx], acc);
    }
  }
  acc = acc * sigm(acc);
  xc[((size_t)b*4096+p)*192 + tid] = acc;
}

// ---------------- K3: x_proj GEMM + dt_proj + softplus, scatter to scan order ----------------
// grid (64,8), block 320.  64 pos x 160 (padded 4*40) outputs, K=192.
__global__ __launch_bounds__(320) void k3_proj(
    const float* __restrict__ xc, const float* __restrict__ xpwTp,
    const float* __restrict__ dtwT, const float* __restrict__ dtb,
    float* __restrict__ deltaS, float* __restrict__ BsS, float* __restrict__ CsS)
{
  __shared__ float sm[192*68];  // phase1: xcT[192][68-pad]; phase2: xdbl[64][160]
  int tid = threadIdx.x;
  int mt = blockIdx.x, b = blockIdx.y;
  int g0 = mt*64;
  const float* xcb = xc + ((size_t)(b*4096 + g0))*192;
  for(int idx=tid; idx<12288; idx+=320){
    int pp = idx/192, d = idx - pp*192;
    sm[d*68+pp] = xcb[idx];
  }
  __syncthreads();
  int tm = tid/40, tn = tid - tm*40;
  float acc[8][4];
  #pragma unroll
  for(int i=0;i<8;i++){acc[i][0]=0.f;acc[i][1]=0.f;acc[i][2]=0.f;acc[i][3]=0.f;}
  const float* wb = xpwTp + tn*4;
  for(int kk=0;kk<192;kk++){
    float4 w4 = *(const float4*)(wb + kk*160);
    float4 a0 = *(const float4*)&sm[kk*68 + tm*8];
    float4 a1 = *(const float4*)&sm[kk*68 + tm*8 + 4];
    float av[8]={a0.x,a0.y,a0.z,a0.w,a1.x,a1.y,a1.z,a1.w};
    #pragma unroll
    for(int i=0;i<8;i++){
      acc[i][0]=fmaf(av[i],w4.x,acc[i][0]);
      acc[i][1]=fmaf(av[i],w4.y,acc[i][1]);
      acc[i][2]=fmaf(av[i],w4.z,acc[i][2]);
      acc[i][3]=fmaf(av[i],w4.w,acc[i][3]);
    }
  }
  __syncthreads();
  #pragma unroll
  for(int i=0;i<8;i++)
    *(float4*)&sm[(tm*8+i)*160 + tn*4] = make_float4(acc[i][0],acc[i][1],acc[i][2],acc[i][3]);
  __syncthreads();
  // delta = softplus(dtw @ xdbl[:6] + bias), scattered to scan order
  for(int idx=tid; idx<49152; idx+=320){
    int d = idx % 192;
    int k = (idx/192)&3;
    int pos = idx/768;
    int l = perm_kl(k, g0+pos);
    float a = dtb[k*192+d];
    #pragma unroll
    for(int r=0;r<6;r++)
      a = fmaf(sm[pos*160 + k*40 + r], dtwT[(k*6+r)*192 + d], a);
    deltaS[(((size_t)(b*4+k))*4096 + l)*192 + d] = softplus_(a);
  }
  // Bs / Cs scatter
  for(int idx=tid; idx<8192; idx+=320){
    int c = idx&31, k = (idx>>5)&3, pos = idx>>7;
    int l = perm_kl(k, g0+pos);
    float v = sm[pos*160 + k*40 + 6 + c];
    size_t row = ((size_t)(b*4+k))*4096 + l;
    if(c<16) BsS[row*16+c]=v; else CsS[row*16+c-16]=v;
  }
}

// ---------------- K4a: per-chunk local scan (h_start=0) ----------------
__global__ __launch_bounds__(192) void k4a_scanlocal(
    const float* __restrict__ deltaS, const float* __restrict__ xc,
    const float* __restrict__ BsS, const float* __restrict__ alog,
    float* __restrict__ localH, float* __restrict__ decayT)
{
  int d = threadIdx.x;
  int ch = blockIdx.x, k = blockIdx.y, b = blockIdx.z;
  float A[16];
  {
    const float4* ap = (const float4*)(alog + (k*192+d)*16);
    float4 a0=ap[0],a1=ap[1],a2=ap[2],a3=ap[3];
    float t[16]={a0.x,a0.y,a0.z,a0.w,a1.x,a1.y,a1.z,a1.w,a2.x,a2.y,a2.z,a2.w,a3.x,a3.y,a3.z,a3.w};
    #pragma unroll
    for(int n=0;n<16;n++) A[n] = -__expf(t[n]);
  }
  float h[16];
  #pragma unroll
  for(int n=0;n<16;n++) h[n]=0.f;
  float S=0.f;
  size_t rbase = ((size_t)(b*4+k))*4096 + ch*64;
  const float* dP = deltaS + rbase*192 + d;
  const float* bP = BsS + rbase*16;
  const float* xb = xc + (size_t)b*4096*192 + d;
  for(int i=0;i<64;i++){
    float delta = dP[(size_t)i*192];
    int p = perm_kl(k, ch*64+i);
    float u = xb[(size_t)p*192];
    const float4* Bv = (const float4*)(bP + i*16);
    float4 b0=Bv[0],b1=Bv[1],b2=Bv[2],b3=Bv[3];
    float Bn[16]={b0.x,b0.y,b0.z,b0.w,b1.x,b1.y,b1.z,b1.w,b2.x,b2.y,b2.z,b2.w,b3.x,b3.y,b3.z,b3.w};
    float du = delta*u;
    S += delta;
    #pragma unroll
    for(int n=0;n<16;n++)
      h[n] = fmaf(h[n], __expf(delta*A[n]), du*Bn[n]);
  }
  float* lh = localH + ((((size_t)(b*4+k))*64 + ch)*192 + d)*16;
  float* dt = decayT + ((((size_t)(b*4+k))*64 + ch)*192 + d)*16;
  #pragma unroll
  for(int n4=0;n4<4;n4++){
    *(float4*)(lh + n4*4) = make_float4(h[n4*4],h[n4*4+1],h[n4*4+2],h[n4*4+3]);
    *(float4*)(dt + n4*4) = make_float4(__expf(A[n4*4]*S),__expf(A[n4*4+1]*S),
                                        __expf(A[n4*4+2]*S),__expf(A[n4*4+3]*S));
  }
}

// ---------------- K4b: chain chunk states; localH becomes h_in (state BEFORE chunk) ----------------
__global__ __launch_bounds__(256) void k4b_chain(
    float* __restrict__ localH, const float* __restrict__ decayT)
{
  int g = blockIdx.x*256 + threadIdx.x;   // 98304 = 32 bk * 3072 dn
  int bk = g/3072, dn = g - bk*3072;
  float hv = 0.f;
  size_t base = (size_t)bk*64*3072 + dn;
  for(int ch=0; ch<64; ch++){
    size_t idx = base + (size_t)ch*3072;
    float loc = localH[idx], dec = decayT[idx];
    localH[idx] = hv;
    hv = fmaf(hv, dec, loc);
  }
}

// ---------------- K4c: full scan with correct h_in, writes y (+Ds*u) over deltaS ----------------
__global__ __launch_bounds__(192) void k4c_scanfull(
    float* __restrict__ dy, const float* __restrict__ xc,
    const float* __restrict__ BsS, const float* __restrict__ CsS,
    const float* __restrict__ alog, const float* __restrict__ hin,
    const float* __restrict__ Dsv)
{
  int d = threadIdx.x;
  int ch = blockIdx.x, k = blockIdx.y, b = blockIdx.z;
  float A[16];
  {
    const float4* ap = (const float4*)(alog + (k*192+d)*16);
    float4 a0=ap[0],a1=ap[1],a2=ap[2],a3=ap[3];
    float t[16]={a0.x,a0.y,a0.z,a0.w,a1.x,a1.y,a1.z,a1.w,a2.x,a2.y,a2.z,a2.w,a3.x,a3.y,a3.z,a3.w};
    #pragma unroll
    for(int n=0;n<16;n++) A[n] = -__expf(t[n]);
  }
  float h[16];
  {
    const float4* hp = (const float4*)(hin + ((((size_t)(b*4+k))*64 + ch)*192 + d)*16);
    float4 h0=hp[0],h1=hp[1],h2=hp[2],h3=hp[3];
    h[0]=h0.x;h[1]=h0.y;h[2]=h0.z;h[3]=h0.w;h[4]=h1.x;h[5]=h1.y;h[6]=h1.z;h[7]=h1.w;
    h[8]=h2.x;h[9]=h2.y;h[10]=h2.z;h[11]=h2.w;h[12]=h3.x;h[13]=h3.y;h[14]=h3.z;h[15]=h3.w;
  }
  float dsv = Dsv[k*192+d];
  size_t rbase = ((size_t)(b*4+k))*4096 + ch*64;
  float* dP = dy + rbase*192 + d;
  const float* bP = BsS + rbase*16;
  const float* cP = CsS + rbase*16;
  const float* xb = xc + (size_t)b*4096*192 + d;
  for(int i=0;i<64;i++){
    float delta = dP[(size_t)i*192];
    int p = perm_kl(k, ch*64+i);
    float u = xb[(size_t)p*192];
    const float4* Bv = (const float4*)(bP + i*16);
    float4 b0=Bv[0],b1=Bv[1],b2=Bv[2],b3=Bv[3];
    float Bn[16]={b0.x,b0.y,b0.z,b0.w,b1.x,b1.y,b1.z,b1.w,b2.x,b2.y,b2.z,b2.w,b3.x,b3.y,b3.z,b3.w};
    const float4* Cv = (const float4*)(cP + i*16);
    float4 c0=Cv[0],c1=Cv[1],c2=Cv[2],c3=Cv[3];
    float Cn[16]={c0.x,c0.y,c0.z,c0.w,c1.x,c1.y,c1.z,c1.w,c2.x,c2.y,c2.z,c2.w,c3.x,c3.y,c3.z,c3.w};
    float du = delta*u;
    float y = 0.f;
    #pragma unroll
    for(int n=0;n<16;n++){
      h[n] = fmaf(h[n], __expf(delta*A[n]), du*Bn[n]);
      y = fmaf(h[n], Cn[n], y);
    }
    dP[(size_t)i*192] = fmaf(dsv, u, y);
  }
}

// ---------------- K5: 4-direction combine + out_norm LN + silu(z) + out_proj + resid ----------------
__global__ __launch_bounds__(192) void k5_combine(
    const float* __restrict__ yS, const float* __restrict__ z, const float* __restrict__ xT,
    const float* __restrict__ onw, const float* __restrict__ onb,
    const float* __restrict__ opwT, float* __restrict__ out_pre)
{
  __shared__ float yo_s[192];
  __shared__ float red[8];
  __shared__ float stats[2];
  int d = threadIdx.x;
  int p = blockIdx.x, b = blockIdx.y;
  int l1 = ((p&63)<<6)|(p>>6);
  size_t base = (size_t)b*4*4096;
  float yv = yS[(base + p)*192 + d]
           + yS[(base + 4096 + l1)*192 + d]
           + yS[(base + 2*4096 + (4095-p))*192 + d]
           + yS[(base + 3*4096 + (4095-l1))*192 + d];
  float s1 = yv, s2 = yv*yv;
  #pragma unroll
  for(int off=32; off>=1; off>>=1){ s1 += __shfl_xor(s1,off); s2 += __shfl_xor(s2,off); }
  int wid = d>>6;
  if((d&63)==0){ red[wid]=s1; red[4+wid]=s2; }
  __syncthreads();
  if(d==0){
    float t1=red[0]+red[1]+red[2], t2=red[4]+red[5]+red[6];
    float mu = t1*(1.f/192.f);
    stats[0]=mu; stats[1]=rsqrtf(t2*(1.f/192.f)-mu*mu+1e-5f);
  }
  __syncthreads();
  float zz = z[((size_t)b*4096+p)*192 + d];
  float yo = (yv-stats[0])*stats[1]*onw[d]+onb[d];
  yo *= zz*sigm(zz);
  yo_s[d]=yo;
  __syncthreads();
  if(d<96){
    float acc = xT[((size_t)b*4096+p)*96 + d];
    const float* wb2 = opwT + d;
    #pragma unroll 4
    for(int dd=0;dd<192;dd++)
      acc = fmaf(yo_s[dd], wb2[dd*96], acc);
    out_pre[((size_t)b*4096+p)*96 + d] = acc;
  }
}

// ---------------- K6: patch merge + LN + pm_red ----------------
__global__ __launch_bounds__(192) void k6_pm(
    const float* __restrict__ out_pre, const float* __restrict__ pmw, const float* __restrict__ pmb,
    const float* __restrict__ pmwT, float* __restrict__ outp)
{
  __shared__ float xm[8*388];
  __shared__ float xo[8*193];
  __shared__ float mus[8], rss[8];
  int tid = threadIdx.x;
  int jt = blockIdx.x, i = blockIdx.y, b = blockIdx.z;
  for(int idx=tid; idx<3072; idx+=192){
    int pj = idx/384, n = idx - pj*384;
    int q = n/96, c = n - q*96;
    int j = jt*8 + pj;
    int h2 = 2*i + (q&1), w2 = 2*j + (q>>1);
    xm[pj*388+n] = out_pre[((size_t)b*4096 + h2*64 + w2)*96 + c];
  }
  __syncthreads();
  if(tid<8){
    float s=0.f,q=0.f;
    for(int n=0;n<384;n++){ float v=xm[tid*388+n]; s+=v; q+=v*v; }
    float mu=s*(1.f/384.f);
    mus[tid]=mu; rss[tid]=rsqrtf(q*(1.f/384.f)-mu*mu+1e-5f);
  }
  __syncthreads();
  for(int idx=tid; idx<3072; idx+=192){
    int pj = idx/384, n = idx - pj*384;
    xm[pj*388+n] = (xm[pj*388+n]-mus[pj])*rss[pj]*pmw[n]+pmb[n];
  }
  __syncthreads();
  float acc[8];
  #pragma unroll
  for(int pj=0;pj<8;pj++) acc[pj]=0.f;
  const float* wb = pmwT + tid;
  for(int n4=0;n4<96;n4++){
    float w0=wb[(n4*4+0)*192], w1=wb[(n4*4+1)*192], w2=wb[(n4*4+2)*192], w3=wb[(n4*4+3)*192];
    #pragma unroll
    for(int pj=0;pj<8;pj++){
      float4 v = *(const float4*)&xm[pj*388 + n4*4];
      acc[pj] = fmaf(v.x,w0,fmaf(v.y,w1,fmaf(v.z,w2,fmaf(v.w,w3,acc[pj]))));
    }
  }
  #pragma unroll
  for(int pj=0;pj<8;pj++) xo[pj*193+tid]=acc[pj];
  __syncthreads();
  for(int idx=tid; idx<1536; idx+=192){
    int c2 = idx>>3, pj = idx&7;
    outp[(((size_t)b*192 + c2)*32 + i)*32 + jt*8 + pj] = xo[pj*193+c2];
  }
}

extern "C" void kernel_launch(void* const* d_in, const int* in_sizes, int n_in,
                              void* d_out, int out_size, void* d_ws, size_t ws_size,
                              hipStream_t stream)
{
  const float* x    = (const float*)d_in[0];
  const float* lnw  = (const float*)d_in[1];
  const float* lnb  = (const float*)d_in[2];
  const float* ipw  = (const float*)d_in[3];
  const float* cw   = (const float*)d_in[4];
  const float* cb   = (const float*)d_in[5];
  const float* xpw  = (const float*)d_in[6];
  const float* dtw  = (const float*)d_in[7];
  const float* dtb  = (const float*)d_in[8];
  const float* alog = (const float*)d_in[9];
  const float* Dsv  = (const float*)d_in[10];
  const float* onw  = (const float*)d_in[11];
  const float* onb  = (const float*)d_in[12];
  const float* opw  = (const float*)d_in[13];
  const float* pmnw = (const float*)d_in[14];
  const float* pmnb = (const float*)d_in[15];
  const float* pmrw = (const float*)d_in[16];
  float* out = (float*)d_out;

  float* ws    = (float*)d_ws;
  float* xT    = ws;              // (B,L,96)   3,145,728 f
  float* xp    = xT + 3145728;    // (B,L,192)  6,291,456 f  (later aliased as out_pre)
  float* zb    = xp + 6291456;    // (B,L,192)  6,291,456 f
  float* xcb   = zb + 6291456;    // (B,L,192)  6,291,456 f
  float* dS    = xcb + 6291456;   // (B,K,L,192) 25,165,824 f (delta, then y in-place)
  float* Bs    = dS + 25165824;   // (B,K,L,16)  2,097,152 f
  float* Cs    = Bs + 2097152;    // (B,K,L,16)  2,097,152 f
  float* lH    = Cs + 2097152;    // (B,K,64,192,16) 6,291,456 f
  float* dT    = lH + 6291456;    // same shape     6,291,456 f
  float* ipwT  = dT + 6291456;    // 36864
  float* xpwTp = ipwT + 36864;    // 30720
  float* dtwT  = xpwTp + 30720;   // 4608
  float* opwT  = dtwT + 4608;     // 18432
  float* pmwT  = opwT + 18432;    // 73728   -> total ~244.6 MiB

  k0_prep      <<<dim3(642),    dim3(256), 0, stream>>>(ipw,xpw,dtw,opw,pmrw, ipwT,xpwTp,dtwT,opwT,pmwT);
  k1_ln_inproj <<<dim3(64,3,8), dim3(256), 0, stream>>>(x,lnw,lnb,ipwT, xT,xp,zb);
  k2_conv      <<<dim3(4096,8), dim3(192), 0, stream>>>(xp,cw,cb, xcb);
  k3_proj      <<<dim3(64,8),   dim3(320), 0, stream>>>(xcb,xpwTp,dtwT,dtb, dS,Bs,Cs);
  k4a_scanlocal<<<dim3(64,4,8), dim3(192), 0, stream>>>(dS,xcb,Bs,alog, lH,dT);
  k4b_chain    <<<dim3(384),    dim3(256), 0, stream>>>(lH,dT);
  k4c_scanfull <<<dim3(64,4,8), dim3(192), 0, stream>>>(dS,xcb,Bs,Cs,alog,lH,Dsv);
  k5_combine   <<<dim3(4096,8), dim3(192), 0, stream>>>(dS,zb,xT,onw,onb,opwT, xp);
  k6_pm        <<<dim3(4,32,8), dim3(192), 0, stream>>>(xp,pmnw,pmnb,pmwT, out);
}

// Round 2
// 459.588 us; speedup vs baseline: 1.1783x; 1.1783x over previous
//
#include <hip/hip_runtime.h>
#include <hip/hip_bf16.h>

// C=96 D=192 K=4 N=16 R=6 B=8 H=W=64 L=4096 ; chunked scan: 64 chunks x 64 steps

__device__ __forceinline__ float sigm(float x){ return 1.f/(1.f+__expf(-x)); }
__device__ __forceinline__ float softplus_(float x){ return (x>20.f)? x : __logf(1.f+__expf(x)); }

// involution mapping pixel<->scan index for direction k
__device__ __forceinline__ int perm_kl(int k, int v){
  if(k==0) return v;
  if(k==1) return ((v&63)<<6)|(v>>6);
  if(k==2) return 4095-v;
  int m = 4095-v; return ((m&63)<<6)|(m>>6);
}

// ---------------- K0: weight transposes ----------------
__global__ __launch_bounds__(256) void k0_prep(
    const float* __restrict__ ipw, const float* __restrict__ xpw,
    const float* __restrict__ dtw, const float* __restrict__ opw,
    const float* __restrict__ pmw,
    float* __restrict__ ipwT, float* __restrict__ xpwTp,
    float* __restrict__ dtwT, float* __restrict__ opwT,
    float* __restrict__ pmwT)
{
  int g = blockIdx.x*256 + threadIdx.x;
  if(g < 36864){                       // ipwT[c][n] = in_proj_w[n][c]  (96x384)
    int c = g/384, n = g%384;
    ipwT[g] = ipw[n*96 + c];
  } else if(g < 67584){                // xpwTp[d][k*40+c] (192x160, pad 38->40)
    int t = g - 36864; int d = t/160, n = t - d*160; int k = n/40, c = n - k*40;
    xpwTp[t] = (c < 38) ? xpw[(k*38 + c)*192 + d] : 0.f;
  } else if(g < 72192){                // dtwT[k][r][d] (4x6x192)
    int t = g - 67584; int kr = t/192, d = t - kr*192; int k = kr/6, r = kr - k*6;
    dtwT[t] = dtw[(k*192 + d)*6 + r];
  } else if(g < 90624){                // opwT[d][c] (192x96)
    int t = g - 72192; int d = t/96, c = t - d*96;
    opwT[t] = opw[c*192 + d];
  } else if(g < 164352){               // pmwT[n][cc] (384x192)
    int t = g - 90624; int n = t/192, c2 = t - n*192;
    pmwT[t] = pmw[c2*384 + n];
  }
}

// ---------------- K1: LN1 + in_proj GEMM (+resid transpose) ----------------
// grid (64 mtiles, 3 ntiles, 8 b), block 256.  BM=64 pos, BN=128, K=96.
#define XT_PAD 68
__global__ __launch_bounds__(256) void k1_ln_inproj(
    const float* __restrict__ x, const float* __restrict__ lnw, const float* __restrict__ lnb,
    const float* __restrict__ ipwT, float* __restrict__ xT,
    float* __restrict__ xp, float* __restrict__ z)
{
  __shared__ float xt[96*XT_PAD];
  __shared__ float lnw_s[96], lnb_s[96], mu_s[64], rs_s[64];
  int tid = threadIdx.x;
  int mt = blockIdx.x, nt = blockIdx.y, b = blockIdx.z;
  int g0 = mt*64;
  const float* xb = x + (size_t)b*96*4096 + g0;
  for(int idx=tid; idx<6144; idx+=256){
    int c = idx>>6, p = idx&63;
    xt[c*XT_PAD+p] = xb[c*4096 + p];
  }
  if(tid<96){ lnw_s[tid]=lnw[tid]; lnb_s[tid]=lnb[tid]; }
  __syncthreads();
  if(nt==0){  // residual: x transposed to (b,l,c)
    float* xTb = xT + ((size_t)(b*4096 + g0))*96;
    for(int idx=tid; idx<6144; idx+=256){
      int p = idx/96, c = idx - p*96;
      xTb[idx] = xt[c*XT_PAD+p];
    }
  }
  if(tid<64){
    float s=0.f,q=0.f;
    for(int c=0;c<96;c++){ float v=xt[c*XT_PAD+tid]; s+=v; q+=v*v; }
    float mu = s*(1.f/96.f);
    mu_s[tid]=mu; rs_s[tid]=rsqrtf(q*(1.f/96.f)-mu*mu+1e-5f);
  }
  __syncthreads();
  for(int idx=tid; idx<6144; idx+=256){
    int c = idx>>6, p = idx&63;
    int a = c*XT_PAD+p;
    xt[a] = (xt[a]-mu_s[p])*rs_s[p]*lnw_s[c]+lnb_s[c];
  }
  __syncthreads();
  int tm = tid>>5, tn = tid&31;
  float acc[8][4];
  #pragma unroll
  for(int i=0;i<8;i++){acc[i][0]=0.f;acc[i][1]=0.f;acc[i][2]=0.f;acc[i][3]=0.f;}
  const float* wbase = ipwT + nt*128 + tn*4;
  for(int kk=0;kk<96;kk++){
    float4 w4 = *(const float4*)(wbase + kk*384);
    float4 a0 = *(const float4*)&xt[kk*XT_PAD + tm*8];
    float4 a1 = *(const float4*)&xt[kk*XT_PAD + tm*8 + 4];
    float av[8]={a0.x,a0.y,a0.z,a0.w,a1.x,a1.y,a1.z,a1.w};
    #pragma unroll
    for(int i=0;i<8;i++){
      acc[i][0]=fmaf(av[i],w4.x,acc[i][0]);
      acc[i][1]=fmaf(av[i],w4.y,acc[i][1]);
      acc[i][2]=fmaf(av[i],w4.z,acc[i][2]);
      acc[i][3]=fmaf(av[i],w4.w,acc[i][3]);
    }
  }
  int n = nt*128 + tn*4;
  #pragma unroll
  for(int i=0;i<8;i++){
    size_t row = (size_t)(b*4096 + g0 + tm*8 + i);
    float4 v = make_float4(acc[i][0],acc[i][1],acc[i][2],acc[i][3]);
    if(n < 192) *(float4*)(xp + row*192 + n) = v;
    else        *(float4*)(z  + row*192 + (n-192)) = v;
  }
}

// ---------------- K2: depthwise 3x3 conv + bias + silu ----------------
__global__ __launch_bounds__(192) void k2_conv(
    const float* __restrict__ xp, const float* __restrict__ cw, const float* __restrict__ cb,
    float* __restrict__ xc)
{
  __shared__ float cw_s[1728];
  int tid = threadIdx.x;
  int p = blockIdx.x, b = blockIdx.y;
  for(int i=tid;i<1728;i+=192) cw_s[i]=cw[i];
  __syncthreads();
  int h = p>>6, w = p&63;
  const float* base = xp + (size_t)b*4096*192 + tid;
  float acc = cb[tid];
  #pragma unroll
  for(int ky=0;ky<3;ky++){
    int hh = h+ky-1;
    if(hh<0||hh>63) continue;
    #pragma unroll
    for(int kx=0;kx<3;kx++){
      int ww = w+kx-1;
      if(ww<0||ww>63) continue;
      acc = fmaf(base[(hh*64+ww)*192], cw_s[tid*9+ky*3+kx], acc);
    }
  }
  acc = acc * sigm(acc);
  xc[((size_t)b*4096+p)*192 + tid] = acc;
}

// ---------------- K3: x_proj GEMM + dt_proj + softplus, scatter to scan order ----------------
// grid (64,8), block 320.  64 pos x 160 (padded 4*40) outputs, K=192.
__global__ __launch_bounds__(320) void k3_proj(
    const float* __restrict__ xc, const float* __restrict__ xpwTp,
    const float* __restrict__ dtwT, const float* __restrict__ dtb,
    float* __restrict__ deltaS, float* __restrict__ BsS, float* __restrict__ CsS)
{
  __shared__ float sm[192*68];  // phase1: xcT[192][68-pad]; phase2: xdbl[64][160]
  int tid = threadIdx.x;
  int mt = blockIdx.x, b = blockIdx.y;
  int g0 = mt*64;
  const float* xcb = xc + ((size_t)(b*4096 + g0))*192;
  for(int idx=tid; idx<12288; idx+=320){
    int pp = idx/192, d = idx - pp*192;
    sm[d*68+pp] = xcb[idx];
  }
  __syncthreads();
  int tm = tid/40, tn = tid - tm*40;
  float acc[8][4];
  #pragma unroll
  for(int i=0;i<8;i++){acc[i][0]=0.f;acc[i][1]=0.f;acc[i][2]=0.f;acc[i][3]=0.f;}
  const float* wb = xpwTp + tn*4;
  for(int kk=0;kk<192;kk++){
    float4 w4 = *(const float4*)(wb + kk*160);
    float4 a0 = *(const float4*)&sm[kk*68 + tm*8];
    float4 a1 = *(const float4*)&sm[kk*68 + tm*8 + 4];
    float av[8]={a0.x,a0.y,a0.z,a0.w,a1.x,a1.y,a1.z,a1.w};
    #pragma unroll
    for(int i=0;i<8;i++){
      acc[i][0]=fmaf(av[i],w4.x,acc[i][0]);
      acc[i][1]=fmaf(av[i],w4.y,acc[i][1]);
      acc[i][2]=fmaf(av[i],w4.z,acc[i][2]);
      acc[i][3]=fmaf(av[i],w4.w,acc[i][3]);
    }
  }
  __syncthreads();
  #pragma unroll
  for(int i=0;i<8;i++)
    *(float4*)&sm[(tm*8+i)*160 + tn*4] = make_float4(acc[i][0],acc[i][1],acc[i][2],acc[i][3]);
  __syncthreads();
  // delta = softplus(dtw @ xdbl[:6] + bias), scattered to scan order
  for(int idx=tid; idx<49152; idx+=320){
    int d = idx % 192;
    int k = (idx/192)&3;
    int pos = idx/768;
    int l = perm_kl(k, g0+pos);
    float a = dtb[k*192+d];
    #pragma unroll
    for(int r=0;r<6;r++)
      a = fmaf(sm[pos*160 + k*40 + r], dtwT[(k*6+r)*192 + d], a);
    deltaS[(((size_t)(b*4+k))*4096 + l)*192 + d] = softplus_(a);
  }
  // Bs / Cs scatter
  for(int idx=tid; idx<8192; idx+=320){
    int c = idx&31, k = (idx>>5)&3, pos = idx>>7;
    int l = perm_kl(k, g0+pos);
    float v = sm[pos*160 + k*40 + 6 + c];
    size_t row = ((size_t)(b*4+k))*4096 + l;
    if(c<16) BsS[row*16+c]=v; else CsS[row*16+c-16]=v;
  }
}

// ---------------- K4a: per-chunk local scan (h_start=0) ----------------
__global__ __launch_bounds__(192) void k4a_scanlocal(
    const float* __restrict__ deltaS, const float* __restrict__ xc,
    const float* __restrict__ BsS, const float* __restrict__ alog,
    float* __restrict__ localH, float* __restrict__ decayT)
{
  int d = threadIdx.x;
  int ch = blockIdx.x, k = blockIdx.y, b = blockIdx.z;
  float A[16];
  {
    const float4* ap = (const float4*)(alog + (k*192+d)*16);
    float4 a0=ap[0],a1=ap[1],a2=ap[2],a3=ap[3];
    float t[16]={a0.x,a0.y,a0.z,a0.w,a1.x,a1.y,a1.z,a1.w,a2.x,a2.y,a2.z,a2.w,a3.x,a3.y,a3.z,a3.w};
    #pragma unroll
    for(int n=0;n<16;n++) A[n] = -__expf(t[n]);
  }
  float h[16];
  #pragma unroll
  for(int n=0;n<16;n++) h[n]=0.f;
  float S=0.f;
  size_t rbase = ((size_t)(b*4+k))*4096 + ch*64;
  const float* dP = deltaS + rbase*192 + d;
  const float* bP = BsS + rbase*16;
  const float* xb = xc + (size_t)b*4096*192 + d;
  for(int i=0;i<64;i++){
    float delta = dP[(size_t)i*192];
    int p = perm_kl(k, ch*64+i);
    float u = xb[(size_t)p*192];
    const float4* Bv = (const float4*)(bP + i*16);
    float4 b0=Bv[0],b1=Bv[1],b2=Bv[2],b3=Bv[3];
    float Bn[16]={b0.x,b0.y,b0.z,b0.w,b1.x,b1.y,b1.z,b1.w,b2.x,b2.y,b2.z,b2.w,b3.x,b3.y,b3.z,b3.w};
    float du = delta*u;
    S += delta;
    #pragma unroll
    for(int n=0;n<16;n++)
      h[n] = fmaf(h[n], __expf(delta*A[n]), du*Bn[n]);
  }
  float* lh = localH + ((((size_t)(b*4+k))*64 + ch)*192 + d)*16;
  float* dt = decayT + ((((size_t)(b*4+k))*64 + ch)*192 + d)*16;
  #pragma unroll
  for(int n4=0;n4<4;n4++){
    *(float4*)(lh + n4*4) = make_float4(h[n4*4],h[n4*4+1],h[n4*4+2],h[n4*4+3]);
    *(float4*)(dt + n4*4) = make_float4(__expf(A[n4*4]*S),__expf(A[n4*4+1]*S),
                                        __expf(A[n4*4+2]*S),__expf(A[n4*4+3]*S));
  }
}

// ---------------- K4b: chain chunk states; localH becomes h_in (state BEFORE chunk) ----------------
__global__ __launch_bounds__(256) void k4b_chain(
    float* __restrict__ localH, const float* __restrict__ decayT)
{
  int g = blockIdx.x*256 + threadIdx.x;   // 98304 = 32 bk * 3072 dn
  int bk = g/3072, dn = g - bk*3072;
  float hv = 0.f;
  size_t base = (size_t)bk*64*3072 + dn;
  for(int ch=0; ch<64; ch++){
    size_t idx = base + (size_t)ch*3072;
    float loc = localH[idx], dec = decayT[idx];
    localH[idx] = hv;
    hv = fmaf(hv, dec, loc);
  }
}

// ---------------- K4c: full scan with correct h_in, writes y (+Ds*u) over deltaS ----------------
__global__ __launch_bounds__(192) void k4c_scanfull(
    float* __restrict__ dy, const float* __restrict__ xc,
    const float* __restrict__ BsS, const float* __restrict__ CsS,
    const float* __restrict__ alog, const float* __restrict__ hin,
    const float* __restrict__ Dsv)
{
  int d = threadIdx.x;
  int ch = blockIdx.x, k = blockIdx.y, b = blockIdx.z;
  float A[16];
  {
    const float4* ap = (const float4*)(alog + (k*192+d)*16);
    float4 a0=ap[0],a1=ap[1],a2=ap[2],a3=ap[3];
    float t[16]={a0.x,a0.y,a0.z,a0.w,a1.x,a1.y,a1.z,a1.w,a2.x,a2.y,a2.z,a2.w,a3.x,a3.y,a3.z,a3.w};
    #pragma unroll
    for(int n=0;n<16;n++) A[n] = -__expf(t[n]);
  }
  float h[16];
  {
    const float4* hp = (const float4*)(hin + ((((size_t)(b*4+k))*64 + ch)*192 + d)*16);
    float4 h0=hp[0],h1=hp[1],h2=hp[2],h3=hp[3];
    h[0]=h0.x;h[1]=h0.y;h[2]=h0.z;h[3]=h0.w;h[4]=h1.x;h[5]=h1.y;h[6]=h1.z;h[7]=h1.w;
    h[8]=h2.x;h[9]=h2.y;h[10]=h2.z;h[11]=h2.w;h[12]=h3.x;h[13]=h3.y;h[14]=h3.z;h[15]=h3.w;
  }
  float dsv = Dsv[k*192+d];
  size_t rbase = ((size_t)(b*4+k))*4096 + ch*64;
  float* dP = dy + rbase*192 + d;
  const float* bP = BsS + rbase*16;
  const float* cP = CsS + rbase*16;
  const float* xb = xc + (size_t)b*4096*192 + d;
  for(int i=0;i<64;i++){
    float delta = dP[(size_t)i*192];
    int p = perm_kl(k, ch*64+i);
    float u = xb[(size_t)p*192];
    const float4* Bv = (const float4*)(bP + i*16);
    float4 b0=Bv[0],b1=Bv[1],b2=Bv[2],b3=Bv[3];
    float Bn[16]={b0.x,b0.y,b0.z,b0.w,b1.x,b1.y,b1.z,b1.w,b2.x,b2.y,b2.z,b2.w,b3.x,b3.y,b3.z,b3.w};
    const float4* Cv = (const float4*)(cP + i*16);
    float4 c0=Cv[0],c1=Cv[1],c2=Cv[2],c3=Cv[3];
    float Cn[16]={c0.x,c0.y,c0.z,c0.w,c1.x,c1.y,c1.z,c1.w,c2.x,c2.y,c2.z,c2.w,c3.x,c3.y,c3.z,c3.w};
    float du = delta*u;
    float y = 0.f;
    #pragma unroll
    for(int n=0;n<16;n++){
      h[n] = fmaf(h[n], __expf(delta*A[n]), du*Bn[n]);
      y = fmaf(h[n], Cn[n], y);
    }
    dP[(size_t)i*192] = fmaf(dsv, u, y);
  }
}

// ---------------- K5: combine + out_norm + silu(z) + out_proj + resid ----------------
// grid (64 mtiles, 8 b), block 256.  Tile = 64 positions.
// Phase1: combine 4 dirs -> LDS yn[64][193]; LN stats 4 thr/pos; gate silu(z);
// Phase2: GEMM 64x192 @ 192x96, 16x16 threads, 4x6 micro-tile, W in 48-row LDS chunks.
#define YPAD 193
__global__ __launch_bounds__(256) void k5_combine(
    const float* __restrict__ yS, const float* __restrict__ z, const float* __restrict__ xT,
    const float* __restrict__ onw, const float* __restrict__ onb,
    const float* __restrict__ opwT, float* __restrict__ out_pre)
{
  __shared__ float yn[64*YPAD];    // 49,408 B
  __shared__ float wsm[48*96];     // 18,432 B
  __shared__ float mu_s[64], rs_s[64];
  int tid = threadIdx.x;
  int mt = blockIdx.x, b = blockIdx.y;
  int g0 = mt*64;
  size_t base = (size_t)b*4*4096;
  for(int idx=tid; idx<12288; idx+=256){
    int p = idx/192, d = idx - p*192;
    int gp = g0 + p;
    int l1 = ((gp&63)<<6)|(gp>>6);
    float v = yS[(base + gp)*192 + d]
            + yS[(base + 4096 + l1)*192 + d]
            + yS[(base + 2*4096 + (4095-gp))*192 + d]
            + yS[(base + 3*4096 + (4095-l1))*192 + d];
    yn[p*YPAD+d] = v;
  }
  __syncthreads();
  {
    int p = tid>>2, q = tid&3;
    float s=0.f, sq=0.f;
    for(int c=q;c<192;c+=4){ float v=yn[p*YPAD+c]; s+=v; sq=fmaf(v,v,sq); }
    s  += __shfl_xor(s,1);  sq += __shfl_xor(sq,1);
    s  += __shfl_xor(s,2);  sq += __shfl_xor(sq,2);
    if(q==0){
      float mu = s*(1.f/192.f);
      mu_s[p]=mu; rs_s[p]=rsqrtf(sq*(1.f/192.f)-mu*mu+1e-5f);
    }
  }
  __syncthreads();
  for(int idx=tid; idx<12288; idx+=256){
    int p = idx/192, d = idx - p*192;
    float zz = z[((size_t)(b*4096+g0+p))*192 + d];
    float v = (yn[p*YPAD+d]-mu_s[p])*rs_s[p]*onw[d]+onb[d];
    yn[p*YPAD+d] = v * zz * sigm(zz);
  }
  __syncthreads();
  int tn = tid&15, tm = tid>>4;    // tn: 6 cols each (96), tm: 4 rows each (64)
  float acc[4][6];
  #pragma unroll
  for(int i=0;i<4;i++)
    #pragma unroll
    for(int j=0;j<6;j++) acc[i][j]=0.f;
  for(int kc=0; kc<4; kc++){
    for(int idx=tid; idx<4608; idx+=256) wsm[idx] = opwT[kc*4608 + idx];
    __syncthreads();
    for(int kk=0;kk<48;kk++){
      float a0 = yn[(tm*4+0)*YPAD + kc*48+kk];
      float a1 = yn[(tm*4+1)*YPAD + kc*48+kk];
      float a2 = yn[(tm*4+2)*YPAD + kc*48+kk];
      float a3 = yn[(tm*4+3)*YPAD + kc*48+kk];
      const float* wr = &wsm[kk*96 + tn*6];
      #pragma unroll
      for(int j=0;j<6;j++){
        float w = wr[j];
        acc[0][j]=fmaf(a0,w,acc[0][j]);
        acc[1][j]=fmaf(a1,w,acc[1][j]);
        acc[2][j]=fmaf(a2,w,acc[2][j]);
        acc[3][j]=fmaf(a3,w,acc[3][j]);
      }
    }
    __syncthreads();
  }
  #pragma unroll
  for(int i=0;i<4;i++){
    size_t row = (size_t)(b*4096 + g0 + tm*4 + i);
    const float* xr = xT + row*96 + tn*6;
    float* orr = out_pre + row*96 + tn*6;
    #pragma unroll
    for(int j=0;j<6;j++) orr[j] = acc[i][j] + xr[j];
  }
}

// ---------------- K6: patch merge + LN + pm_red ----------------
__global__ __launch_bounds__(192) void k6_pm(
    const float* __restrict__ out_pre, const float* __restrict__ pmw, const float* __restrict__ pmb,
    const float* __restrict__ pmwT, float* __restrict__ outp)
{
  __shared__ float xm[8*388];
  __shared__ float xo[8*193];
  __shared__ float mus[8], rss[8];
  int tid = threadIdx.x;
  int jt = blockIdx.x, i = blockIdx.y, b = blockIdx.z;
  for(int idx=tid; idx<3072; idx+=192){
    int pj = idx/384, n = idx - pj*384;
    int q = n/96, c = n - q*96;
    int j = jt*8 + pj;
    int h2 = 2*i + (q&1), w2 = 2*j + (q>>1);
    xm[pj*388+n] = out_pre[((size_t)b*4096 + h2*64 + w2)*96 + c];
  }
  __syncthreads();
  if(tid<8){
    float s=0.f,q=0.f;
    for(int n=0;n<384;n++){ float v=xm[tid*388+n]; s+=v; q+=v*v; }
    float mu=s*(1.f/384.f);
    mus[tid]=mu; rss[tid]=rsqrtf(q*(1.f/384.f)-mu*mu+1e-5f);
  }
  __syncthreads();
  for(int idx=tid; idx<3072; idx+=192){
    int pj = idx/384, n = idx - pj*384;
    xm[pj*388+n] = (xm[pj*388+n]-mus[pj])*rss[pj]*pmw[n]+pmb[n];
  }
  __syncthreads();
  float acc[8];
  #pragma unroll
  for(int pj=0;pj<8;pj++) acc[pj]=0.f;
  const float* wb = pmwT + tid;
  for(int n4=0;n4<96;n4++){
    float w0=wb[(n4*4+0)*192], w1=wb[(n4*4+1)*192], w2=wb[(n4*4+2)*192], w3=wb[(n4*4+3)*192];
    #pragma unroll
    for(int pj=0;pj<8;pj++){
      float4 v = *(const float4*)&xm[pj*388 + n4*4];
      acc[pj] = fmaf(v.x,w0,fmaf(v.y,w1,fmaf(v.z,w2,fmaf(v.w,w3,acc[pj]))));
    }
  }
  #pragma unroll
  for(int pj=0;pj<8;pj++) xo[pj*193+tid]=acc[pj];
  __syncthreads();
  for(int idx=tid; idx<1536; idx+=192){
    int c2 = idx>>3, pj = idx&7;
    outp[(((size_t)b*192 + c2)*32 + i)*32 + jt*8 + pj] = xo[pj*193+c2];
  }
}

extern "C" void kernel_launch(void* const* d_in, const int* in_sizes, int n_in,
                              void* d_out, int out_size, void* d_ws, size_t ws_size,
                              hipStream_t stream)
{
  const float* x    = (const float*)d_in[0];
  const float* lnw  = (const float*)d_in[1];
  const float* lnb  = (const float*)d_in[2];
  const float* ipw  = (const float*)d_in[3];
  const float* cw   = (const float*)d_in[4];
  const float* cb   = (const float*)d_in[5];
  const float* xpw  = (const float*)d_in[6];
  const float* dtw  = (const float*)d_in[7];
  const float* dtb  = (const float*)d_in[8];
  const float* alog = (const float*)d_in[9];
  const float* Dsv  = (const float*)d_in[10];
  const float* onw  = (const float*)d_in[11];
  const float* onb  = (const float*)d_in[12];
  const float* opw  = (const float*)d_in[13];
  const float* pmnw = (const float*)d_in[14];
  const float* pmnb = (const float*)d_in[15];
  const float* pmrw = (const float*)d_in[16];
  float* out = (float*)d_out;

  float* ws    = (float*)d_ws;
  float* xT    = ws;              // (B,L,96)   3,145,728 f
  float* xp    = xT + 3145728;    // (B,L,192)  6,291,456 f  (later aliased as out_pre)
  float* zb    = xp + 6291456;    // (B,L,192)  6,291,456 f
  float* xcb   = zb + 6291456;    // (B,L,192)  6,291,456 f
  float* dS    = xcb + 6291456;   // (B,K,L,192) 25,165,824 f (delta, then y in-place)
  float* Bs    = dS + 25165824;   // (B,K,L,16)  2,097,152 f
  float* Cs    = Bs + 2097152;    // (B,K,L,16)  2,097,152 f
  float* lH    = Cs + 2097152;    // (B,K,64,192,16) 6,291,456 f
  float* dT    = lH + 6291456;    // same shape     6,291,456 f
  float* ipwT  = dT + 6291456;    // 36864
  float* xpwTp = ipwT + 36864;    // 30720
  float* dtwT  = xpwTp + 30720;   // 4608
  float* opwT  = dtwT + 4608;     // 18432
  float* pmwT  = opwT + 18432;    // 73728   -> total ~244.6 MiB

  k0_prep      <<<dim3(642),    dim3(256), 0, stream>>>(ipw,xpw,dtw,opw,pmrw, ipwT,xpwTp,dtwT,opwT,pmwT);
  k1_ln_inproj <<<dim3(64,3,8), dim3(256), 0, stream>>>(x,lnw,lnb,ipwT, xT,xp,zb);
  k2_conv      <<<dim3(4096,8), dim3(192), 0, stream>>>(xp,cw,cb, xcb);
  k3_proj      <<<dim3(64,8),   dim3(320), 0, stream>>>(xcb,xpwTp,dtwT,dtb, dS,Bs,Cs);
  k4a_scanlocal<<<dim3(64,4,8), dim3(192), 0, stream>>>(dS,xcb,Bs,alog, lH,dT);
  k4b_chain    <<<dim3(384),    dim3(256), 0, stream>>>(lH,dT);
  k4c_scanfull <<<dim3(64,4,8), dim3(192), 0, stream>>>(dS,xcb,Bs,Cs,alog,lH,Dsv);
  k5_combine   <<<dim3(64,8),   dim3(256), 0, stream>>>(dS,zb,xT,onw,onb,opwT, xp);
  k6_pm        <<<dim3(4,32,8), dim3(192), 0, stream>>>(xp,pmnw,pmnb,pmwT, out);
}

// Round 3
// 359.839 us; speedup vs baseline: 1.5049x; 1.2772x over previous
//
#include <hip/hip_runtime.h>
#include <hip/hip_bf16.h>

// C=96 D=192 K=4 N=16 R=6 B=8 H=W=64 L=4096 ; chunked scan: 64 chunks x 64 steps
// x_dbl compact layout per (b,pos): [k*40 + {0..5 dt, 6..7 pad, 8..23 B, 24..39 C}]

__device__ __forceinline__ float sigm(float x){ return 1.f/(1.f+__expf(-x)); }
__device__ __forceinline__ float softplus_(float x){ return (x>20.f)? x : __logf(1.f+__expf(x)); }

// involution mapping pixel<->scan index for direction k
__device__ __forceinline__ int perm_kl(int k, int v){
  if(k==0) return v;
  if(k==1) return ((v&63)<<6)|(v>>6);
  if(k==2) return 4095-v;
  int m = 4095-v; return ((m&63)<<6)|(m>>6);
}

// ---------------- K0: weight transposes ----------------
__global__ __launch_bounds__(256) void k0_prep(
    const float* __restrict__ ipw, const float* __restrict__ xpw,
    const float* __restrict__ dtw, const float* __restrict__ opw,
    const float* __restrict__ pmw,
    float* __restrict__ ipwT, float* __restrict__ xpwTp,
    float* __restrict__ dtwT, float* __restrict__ opwT,
    float* __restrict__ pmwT)
{
  int g = blockIdx.x*256 + threadIdx.x;
  if(g < 36864){                       // ipwT[c][n] = in_proj_w[n][c]  (96x384)
    int c = g/384, n = g%384;
    ipwT[g] = ipw[n*96 + c];
  } else if(g < 67584){                // xpwTp[d][k*40+m(c)] (192x160) with gap at 6,7
    int t = g - 36864; int dd = t/160, n = t - dd*160; int k = n/40, c = n - k*40;
    float v;
    if(c < 6)       v = xpw[(k*38 + c)*192 + dd];
    else if(c < 8)  v = 0.f;
    else            v = xpw[(k*38 + (c-2))*192 + dd];
    xpwTp[t] = v;
  } else if(g < 72192){                // dtwT[k][r][d] (4x6x192)
    int t = g - 67584; int kr = t/192, d = t - kr*192; int k = kr/6, r = kr - k*6;
    dtwT[t] = dtw[(k*192 + d)*6 + r];
  } else if(g < 90624){                // opwT[d][c] (192x96)
    int t = g - 72192; int d = t/96, c = t - d*96;
    opwT[t] = opw[c*192 + d];
  } else if(g < 164352){               // pmwT[n][cc] (384x192)
    int t = g - 90624; int n = t/192, c2 = t - n*192;
    pmwT[t] = pmw[c2*384 + n];
  }
}

// ---------------- K1: LN1 + in_proj GEMM (+resid transpose) ----------------
#define XT_PAD 68
__global__ __launch_bounds__(256) void k1_ln_inproj(
    const float* __restrict__ x, const float* __restrict__ lnw, const float* __restrict__ lnb,
    const float* __restrict__ ipwT, float* __restrict__ xT,
    float* __restrict__ xp, float* __restrict__ z)
{
  __shared__ float xt[96*XT_PAD];
  __shared__ float lnw_s[96], lnb_s[96], mu_s[64], rs_s[64];
  int tid = threadIdx.x;
  int mt = blockIdx.x, nt = blockIdx.y, b = blockIdx.z;
  int g0 = mt*64;
  const float* xb = x + (size_t)b*96*4096 + g0;
  for(int idx=tid; idx<6144; idx+=256){
    int c = idx>>6, p = idx&63;
    xt[c*XT_PAD+p] = xb[c*4096 + p];
  }
  if(tid<96){ lnw_s[tid]=lnw[tid]; lnb_s[tid]=lnb[tid]; }
  __syncthreads();
  if(nt==0){  // residual: x transposed to (b,l,c)
    float* xTb = xT + ((size_t)(b*4096 + g0))*96;
    for(int idx=tid; idx<6144; idx+=256){
      int p = idx/96, c = idx - p*96;
      xTb[idx] = xt[c*XT_PAD+p];
    }
  }
  if(tid<64){
    float s=0.f,q=0.f;
    for(int c=0;c<96;c++){ float v=xt[c*XT_PAD+tid]; s+=v; q+=v*v; }
    float mu = s*(1.f/96.f);
    mu_s[tid]=mu; rs_s[tid]=rsqrtf(q*(1.f/96.f)-mu*mu+1e-5f);
  }
  __syncthreads();
  for(int idx=tid; idx<6144; idx+=256){
    int c = idx>>6, p = idx&63;
    int a = c*XT_PAD+p;
    xt[a] = (xt[a]-mu_s[p])*rs_s[p]*lnw_s[c]+lnb_s[c];
  }
  __syncthreads();
  int tm = tid>>5, tn = tid&31;
  float acc[8][4];
  #pragma unroll
  for(int i=0;i<8;i++){acc[i][0]=0.f;acc[i][1]=0.f;acc[i][2]=0.f;acc[i][3]=0.f;}
  const float* wbase = ipwT + nt*128 + tn*4;
  for(int kk=0;kk<96;kk++){
    float4 w4 = *(const float4*)(wbase + kk*384);
    float4 a0 = *(const float4*)&xt[kk*XT_PAD + tm*8];
    float4 a1 = *(const float4*)&xt[kk*XT_PAD + tm*8 + 4];
    float av[8]={a0.x,a0.y,a0.z,a0.w,a1.x,a1.y,a1.z,a1.w};
    #pragma unroll
    for(int i=0;i<8;i++){
      acc[i][0]=fmaf(av[i],w4.x,acc[i][0]);
      acc[i][1]=fmaf(av[i],w4.y,acc[i][1]);
      acc[i][2]=fmaf(av[i],w4.z,acc[i][2]);
      acc[i][3]=fmaf(av[i],w4.w,acc[i][3]);
    }
  }
  int n = nt*128 + tn*4;
  #pragma unroll
  for(int i=0;i<8;i++){
    size_t row = (size_t)(b*4096 + g0 + tm*8 + i);
    float4 v = make_float4(acc[i][0],acc[i][1],acc[i][2],acc[i][3]);
    if(n < 192) *(float4*)(xp + row*192 + n) = v;
    else        *(float4*)(z  + row*192 + (n-192)) = v;
  }
}

// ---------------- K2: depthwise 3x3 conv + bias + silu (4 pixels/block) ----------------
__global__ __launch_bounds__(192) void k2_conv(
    const float* __restrict__ xp, const float* __restrict__ cw, const float* __restrict__ cb,
    float* __restrict__ xc)
{
  __shared__ float cw_s[1728];
  int tid = threadIdx.x;
  int pq = blockIdx.x, b = blockIdx.y;
  for(int i=tid;i<1728;i+=192) cw_s[i]=cw[i];
  __syncthreads();
  int p0 = pq*4;
  int h = p0>>6, w0 = p0&63;
  const float* base = xp + (size_t)b*4096*192 + tid;
  const float* wp = &cw_s[tid*9];
  float bias = cb[tid];
  float acc[4] = {bias,bias,bias,bias};
  #pragma unroll
  for(int ky=0;ky<3;ky++){
    int hh = h+ky-1;
    if(hh<0||hh>63) continue;
    float v[6];
    #pragma unroll
    for(int xx=0;xx<6;xx++){
      int ww = w0-1+xx;
      v[xx] = (ww>=0 && ww<64) ? base[((size_t)(hh*64+ww))*192] : 0.f;
    }
    float wk0=wp[ky*3], wk1=wp[ky*3+1], wk2=wp[ky*3+2];
    #pragma unroll
    for(int j=0;j<4;j++)
      acc[j] = fmaf(v[j],wk0, fmaf(v[j+1],wk1, fmaf(v[j+2],wk2, acc[j])));
  }
  #pragma unroll
  for(int j=0;j<4;j++){
    float a = acc[j];
    a = a * sigm(a);
    xc[((size_t)(b*4096)+p0+j)*192 + tid] = a;
  }
}

// ---------------- K3: x_proj GEMM -> compact x_dbl ----------------
// grid (128,8), block 320. 32 pos x 160 cols, K=192. Natural LDS layout (no conflicts).
__global__ __launch_bounds__(320) void k3_proj(
    const float* __restrict__ xc, const float* __restrict__ xpwTp,
    float* __restrict__ xdbl)
{
  __shared__ float sm[32*192];   // 24 KB
  int tid = threadIdx.x;
  int mt = blockIdx.x, b = blockIdx.y;
  int g0 = mt*32;
  const float* xcb = xc + ((size_t)(b*4096 + g0))*192;
  for(int idx=tid; idx<6144; idx+=320) sm[idx] = xcb[idx];
  __syncthreads();
  int tn = tid%40, tm = tid/40;           // tn: col group (4 cols), tm: row group (4 rows)
  float acc[4][4];
  #pragma unroll
  for(int i=0;i<4;i++){acc[i][0]=0.f;acc[i][1]=0.f;acc[i][2]=0.f;acc[i][3]=0.f;}
  const float* wb = xpwTp + tn*4;
  for(int kk=0;kk<192;kk+=2){
    float4 w0 = *(const float4*)(wb + kk*160);
    float4 w1 = *(const float4*)(wb + (kk+1)*160);
    #pragma unroll
    for(int i=0;i<4;i++){
      float2 a = *(const float2*)&sm[(tm*4+i)*192 + kk];
      acc[i][0] = fmaf(a.x,w0.x, fmaf(a.y,w1.x, acc[i][0]));
      acc[i][1] = fmaf(a.x,w0.y, fmaf(a.y,w1.y, acc[i][1]));
      acc[i][2] = fmaf(a.x,w0.z, fmaf(a.y,w1.z, acc[i][2]));
      acc[i][3] = fmaf(a.x,w0.w, fmaf(a.y,w1.w, acc[i][3]));
    }
  }
  #pragma unroll
  for(int i=0;i<4;i++){
    *(float4*)(xdbl + ((size_t)(b*4096 + g0 + tm*4 + i))*160 + tn*4)
      = make_float4(acc[i][0],acc[i][1],acc[i][2],acc[i][3]);
  }
}

// ---------------- K4a: per-chunk local scan, delta fused (h_start=0) ----------------
__global__ __launch_bounds__(192) void k4a_scanlocal(
    const float* __restrict__ xdbl, const float* __restrict__ xc,
    const float* __restrict__ alog, const float* __restrict__ dtwT,
    const float* __restrict__ dtb,
    float* __restrict__ localH, float* __restrict__ decayT)
{
  int d = threadIdx.x;
  int ch = blockIdx.x, k = blockIdx.y, b = blockIdx.z;
  __shared__ float dtw_s[6*192];
  #pragma unroll
  for(int r=0;r<6;r++) dtw_s[r*192+d] = dtwT[(k*6+r)*192+d];
  __syncthreads();
  float A[16];
  {
    const float4* ap = (const float4*)(alog + (k*192+d)*16);
    float4 a0=ap[0],a1=ap[1],a2=ap[2],a3=ap[3];
    float t[16]={a0.x,a0.y,a0.z,a0.w,a1.x,a1.y,a1.z,a1.w,a2.x,a2.y,a2.z,a2.w,a3.x,a3.y,a3.z,a3.w};
    #pragma unroll
    for(int n=0;n<16;n++) A[n] = -__expf(t[n]);
  }
  bool fast = true;
  #pragma unroll
  for(int n=1;n<16;n++)
    fast = fast && (fabsf(A[n] - (float)(n+1)*A[0]) <= 1e-4f*(float)(n+1)*fabsf(A[0]));
  float dtbv = dtb[k*192+d];
  float h[16];
  #pragma unroll
  for(int n=0;n<16;n++) h[n]=0.f;
  float S=0.f;
  const float* xb = xc + (size_t)b*4096*192 + d;
  size_t prow = (size_t)b*4096;
  for(int i=0;i<64;i++){
    int p = perm_kl(k, ch*64+i);
    const float* row = xdbl + (prow+p)*160 + k*40;
    float u = xb[(size_t)p*192];
    float delta = dtbv;
    #pragma unroll
    for(int r=0;r<6;r++) delta = fmaf(row[r], dtw_s[r*192+d], delta);
    delta = softplus_(delta);
    float4 B0=*(const float4*)(row+8),  B1=*(const float4*)(row+12),
           B2=*(const float4*)(row+16), B3=*(const float4*)(row+20);
    float Bn[16]={B0.x,B0.y,B0.z,B0.w,B1.x,B1.y,B1.z,B1.w,B2.x,B2.y,B2.z,B2.w,B3.x,B3.y,B3.z,B3.w};
    float du = delta*u;
    S += delta;
    if(fast){
      float e1 = __expf(delta*A[0]);
      float e = e1;
      #pragma unroll
      for(int n=0;n<16;n++){ h[n] = fmaf(h[n], e, du*Bn[n]); e *= e1; }
    } else {
      #pragma unroll
      for(int n=0;n<16;n++) h[n] = fmaf(h[n], __expf(delta*A[n]), du*Bn[n]);
    }
  }
  float dec[16];
  if(fast){
    float s1 = __expf(S*A[0]);
    float e = s1;
    #pragma unroll
    for(int n=0;n<16;n++){ dec[n]=e; e*=s1; }
  } else {
    #pragma unroll
    for(int n=0;n<16;n++) dec[n] = __expf(A[n]*S);
  }
  float* lh = localH + ((((size_t)(b*4+k))*64 + ch)*192 + d)*16;
  float* dt = decayT + ((((size_t)(b*4+k))*64 + ch)*192 + d)*16;
  #pragma unroll
  for(int n4=0;n4<4;n4++){
    *(float4*)(lh + n4*4) = make_float4(h[n4*4],h[n4*4+1],h[n4*4+2],h[n4*4+3]);
    *(float4*)(dt + n4*4) = make_float4(dec[n4*4],dec[n4*4+1],dec[n4*4+2],dec[n4*4+3]);
  }
}

// ---------------- K4b: chain chunk states ----------------
__global__ __launch_bounds__(256) void k4b_chain(
    float* __restrict__ localH, const float* __restrict__ decayT)
{
  int g = blockIdx.x*256 + threadIdx.x;   // 98304 = 32 bk * 3072 dn
  int bk = g/3072, dn = g - bk*3072;
  float hv = 0.f;
  size_t base = (size_t)bk*64*3072 + dn;
  for(int ch=0; ch<64; ch++){
    size_t idx = base + (size_t)ch*3072;
    float loc = localH[idx], dec = decayT[idx];
    localH[idx] = hv;
    hv = fmaf(hv, dec, loc);
  }
}

// ---------------- K4c: full scan, delta fused, writes y(+Ds*u) to yB ----------------
__global__ __launch_bounds__(192) void k4c_scanfull(
    const float* __restrict__ xdbl, const float* __restrict__ xc,
    const float* __restrict__ alog, const float* __restrict__ dtwT,
    const float* __restrict__ dtb, const float* __restrict__ hin,
    const float* __restrict__ Dsv, float* __restrict__ yB)
{
  int d = threadIdx.x;
  int ch = blockIdx.x, k = blockIdx.y, b = blockIdx.z;
  __shared__ float dtw_s[6*192];
  #pragma unroll
  for(int r=0;r<6;r++) dtw_s[r*192+d] = dtwT[(k*6+r)*192+d];
  __syncthreads();
  float A[16];
  {
    const float4* ap = (const float4*)(alog + (k*192+d)*16);
    float4 a0=ap[0],a1=ap[1],a2=ap[2],a3=ap[3];
    float t[16]={a0.x,a0.y,a0.z,a0.w,a1.x,a1.y,a1.z,a1.w,a2.x,a2.y,a2.z,a2.w,a3.x,a3.y,a3.z,a3.w};
    #pragma unroll
    for(int n=0;n<16;n++) A[n] = -__expf(t[n]);
  }
  bool fast = true;
  #pragma unroll
  for(int n=1;n<16;n++)
    fast = fast && (fabsf(A[n] - (float)(n+1)*A[0]) <= 1e-4f*(float)(n+1)*fabsf(A[0]));
  float dtbv = dtb[k*192+d];
  float h[16];
  {
    const float4* hp = (const float4*)(hin + ((((size_t)(b*4+k))*64 + ch)*192 + d)*16);
    float4 h0=hp[0],h1=hp[1],h2=hp[2],h3=hp[3];
    h[0]=h0.x;h[1]=h0.y;h[2]=h0.z;h[3]=h0.w;h[4]=h1.x;h[5]=h1.y;h[6]=h1.z;h[7]=h1.w;
    h[8]=h2.x;h[9]=h2.y;h[10]=h2.z;h[11]=h2.w;h[12]=h3.x;h[13]=h3.y;h[14]=h3.z;h[15]=h3.w;
  }
  float dsv = Dsv[k*192+d];
  const float* xb = xc + (size_t)b*4096*192 + d;
  size_t prow = (size_t)b*4096;
  size_t rbase = ((size_t)(b*4+k))*4096 + ch*64;
  float* yP = yB + rbase*192 + d;
  for(int i=0;i<64;i++){
    int p = perm_kl(k, ch*64+i);
    const float* row = xdbl + (prow+p)*160 + k*40;
    float u = xb[(size_t)p*192];
    float delta = dtbv;
    #pragma unroll
    for(int r=0;r<6;r++) delta = fmaf(row[r], dtw_s[r*192+d], delta);
    delta = softplus_(delta);
    float4 B0=*(const float4*)(row+8),  B1=*(const float4*)(row+12),
           B2=*(const float4*)(row+16), B3=*(const float4*)(row+20);
    float Bn[16]={B0.x,B0.y,B0.z,B0.w,B1.x,B1.y,B1.z,B1.w,B2.x,B2.y,B2.z,B2.w,B3.x,B3.y,B3.z,B3.w};
    float4 C0=*(const float4*)(row+24), C1=*(const float4*)(row+28),
           C2=*(const float4*)(row+32), C3=*(const float4*)(row+36);
    float Cn[16]={C0.x,C0.y,C0.z,C0.w,C1.x,C1.y,C1.z,C1.w,C2.x,C2.y,C2.z,C2.w,C3.x,C3.y,C3.z,C3.w};
    float du = delta*u;
    float y = 0.f;
    if(fast){
      float e1 = __expf(delta*A[0]);
      float e = e1;
      #pragma unroll
      for(int n=0;n<16;n++){ h[n] = fmaf(h[n], e, du*Bn[n]); y = fmaf(h[n], Cn[n], y); e *= e1; }
    } else {
      #pragma unroll
      for(int n=0;n<16;n++){ h[n] = fmaf(h[n], __expf(delta*A[n]), du*Bn[n]); y = fmaf(h[n], Cn[n], y); }
    }
    yP[(size_t)i*192] = fmaf(dsv, u, y);
  }
}

// ---------------- K5: combine + out_norm + silu(z) + out_proj + resid ----------------
#define YPAD 193
__global__ __launch_bounds__(256) void k5_combine(
    const float* __restrict__ yS, const float* __restrict__ z, const float* __restrict__ xT,
    const float* __restrict__ onw, const float* __restrict__ onb,
    const float* __restrict__ opwT, float* __restrict__ out_pre)
{
  __shared__ float yn[64*YPAD];    // 49,408 B
  __shared__ float wsm[48*96];     // 18,432 B
  __shared__ float mu_s[64], rs_s[64];
  int tid = threadIdx.x;
  int mt = blockIdx.x, b = blockIdx.y;
  int g0 = mt*64;
  size_t base = (size_t)b*4*4096;
  for(int idx=tid; idx<12288; idx+=256){
    int p = idx/192, d = idx - p*192;
    int gp = g0 + p;
    int l1 = ((gp&63)<<6)|(gp>>6);
    float v = yS[(base + gp)*192 + d]
            + yS[(base + 4096 + l1)*192 + d]
            + yS[(base + 2*4096 + (4095-gp))*192 + d]
            + yS[(base + 3*4096 + (4095-l1))*192 + d];
    yn[p*YPAD+d] = v;
  }
  __syncthreads();
  {
    int p = tid>>2, q = tid&3;
    float s=0.f, sq=0.f;
    for(int c=q;c<192;c+=4){ float v=yn[p*YPAD+c]; s+=v; sq=fmaf(v,v,sq); }
    s  += __shfl_xor(s,1);  sq += __shfl_xor(sq,1);
    s  += __shfl_xor(s,2);  sq += __shfl_xor(sq,2);
    if(q==0){
      float mu = s*(1.f/192.f);
      mu_s[p]=mu; rs_s[p]=rsqrtf(sq*(1.f/192.f)-mu*mu+1e-5f);
    }
  }
  __syncthreads();
  for(int idx=tid; idx<12288; idx+=256){
    int p = idx/192, d = idx - p*192;
    float zz = z[((size_t)(b*4096+g0+p))*192 + d];
    float v = (yn[p*YPAD+d]-mu_s[p])*rs_s[p]*onw[d]+onb[d];
    yn[p*YPAD+d] = v * zz * sigm(zz);
  }
  __syncthreads();
  int tn = tid&15, tm = tid>>4;    // tn: 6 cols each (96), tm: 4 rows each (64)
  float acc[4][6];
  #pragma unroll
  for(int i=0;i<4;i++)
    #pragma unroll
    for(int j=0;j<6;j++) acc[i][j]=0.f;
  for(int kc=0; kc<4; kc++){
    for(int idx=tid; idx<4608; idx+=256) wsm[idx] = opwT[kc*4608 + idx];
    __syncthreads();
    for(int kk=0;kk<48;kk++){
      float a0 = yn[(tm*4+0)*YPAD + kc*48+kk];
      float a1 = yn[(tm*4+1)*YPAD + kc*48+kk];
      float a2 = yn[(tm*4+2)*YPAD + kc*48+kk];
      float a3 = yn[(tm*4+3)*YPAD + kc*48+kk];
      const float* wr = &wsm[kk*96 + tn*6];
      #pragma unroll
      for(int j=0;j<6;j++){
        float w = wr[j];
        acc[0][j]=fmaf(a0,w,acc[0][j]);
        acc[1][j]=fmaf(a1,w,acc[1][j]);
        acc[2][j]=fmaf(a2,w,acc[2][j]);
        acc[3][j]=fmaf(a3,w,acc[3][j]);
      }
    }
    __syncthreads();
  }
  #pragma unroll
  for(int i=0;i<4;i++){
    size_t row = (size_t)(b*4096 + g0 + tm*4 + i);
    const float* xr = xT + row*96 + tn*6;
    float* orr = out_pre + row*96 + tn*6;
    #pragma unroll
    for(int j=0;j<6;j++) orr[j] = acc[i][j] + xr[j];
  }
}

// ---------------- K6: patch merge + LN + pm_red ----------------
__global__ __launch_bounds__(192) void k6_pm(
    const float* __restrict__ out_pre, const float* __restrict__ pmw, const float* __restrict__ pmb,
    const float* __restrict__ pmwT, float* __restrict__ outp)
{
  __shared__ float xm[8*388];
  __shared__ float xo[8*193];
  __shared__ float mus[8], rss[8];
  int tid = threadIdx.x;
  int jt = blockIdx.x, i = blockIdx.y, b = blockIdx.z;
  for(int idx=tid; idx<3072; idx+=192){
    int pj = idx/384, n = idx - pj*384;
    int q = n/96, c = n - q*96;
    int j = jt*8 + pj;
    int h2 = 2*i + (q&1), w2 = 2*j + (q>>1);
    xm[pj*388+n] = out_pre[((size_t)b*4096 + h2*64 + w2)*96 + c];
  }
  __syncthreads();
  if(tid<8){
    float s=0.f,q=0.f;
    for(int n=0;n<384;n++){ float v=xm[tid*388+n]; s+=v; q+=v*v; }
    float mu=s*(1.f/384.f);
    mus[tid]=mu; rss[tid]=rsqrtf(q*(1.f/384.f)-mu*mu+1e-5f);
  }
  __syncthreads();
  for(int idx=tid; idx<3072; idx+=192){
    int pj = idx/384, n = idx - pj*384;
    xm[pj*388+n] = (xm[pj*388+n]-mus[pj])*rss[pj]*pmw[n]+pmb[n];
  }
  __syncthreads();
  float acc[8];
  #pragma unroll
  for(int pj=0;pj<8;pj++) acc[pj]=0.f;
  const float* wb = pmwT + tid;
  for(int n4=0;n4<96;n4++){
    float w0=wb[(n4*4+0)*192], w1=wb[(n4*4+1)*192], w2=wb[(n4*4+2)*192], w3=wb[(n4*4+3)*192];
    #pragma unroll
    for(int pj=0;pj<8;pj++){
      float4 v = *(const float4*)&xm[pj*388 + n4*4];
      acc[pj] = fmaf(v.x,w0,fmaf(v.y,w1,fmaf(v.z,w2,fmaf(v.w,w3,acc[pj]))));
    }
  }
  #pragma unroll
  for(int pj=0;pj<8;pj++) xo[pj*193+tid]=acc[pj];
  __syncthreads();
  for(int idx=tid; idx<1536; idx+=192){
    int c2 = idx>>3, pj = idx&7;
    outp[(((size_t)b*192 + c2)*32 + i)*32 + jt*8 + pj] = xo[pj*193+c2];
  }
}

extern "C" void kernel_launch(void* const* d_in, const int* in_sizes, int n_in,
                              void* d_out, int out_size, void* d_ws, size_t ws_size,
                              hipStream_t stream)
{
  const float* x    = (const float*)d_in[0];
  const float* lnw  = (const float*)d_in[1];
  const float* lnb  = (const float*)d_in[2];
  const float* ipw  = (const float*)d_in[3];
  const float* cw   = (const float*)d_in[4];
  const float* cb   = (const float*)d_in[5];
  const float* xpw  = (const float*)d_in[6];
  const float* dtw  = (const float*)d_in[7];
  const float* dtb  = (const float*)d_in[8];
  const float* alog = (const float*)d_in[9];
  const float* Dsv  = (const float*)d_in[10];
  const float* onw  = (const float*)d_in[11];
  const float* onb  = (const float*)d_in[12];
  const float* opw  = (const float*)d_in[13];
  const float* pmnw = (const float*)d_in[14];
  const float* pmnb = (const float*)d_in[15];
  const float* pmrw = (const float*)d_in[16];
  float* out = (float*)d_out;

  float* ws    = (float*)d_ws;
  float* xT    = ws;              // (B,L,96)   3,145,728 f
  float* xpb   = xT + 3145728;    // (B,L,192)  6,291,456 f ; aliased: xdbl (k3..k4c), out_pre (k5..k6)
  float* zb    = xpb + 6291456;   // (B,L,192)  6,291,456 f
  float* xcb   = zb + 6291456;    // (B,L,192)  6,291,456 f
  float* yB    = xcb + 6291456;   // (B,K,L,192) 25,165,824 f
  float* lH    = yB + 25165824;   // (B,K,64,192,16) 6,291,456 f
  float* dT    = lH + 6291456;    // same           6,291,456 f
  float* ipwT  = dT + 6291456;    // 36864
  float* xpwTp = ipwT + 36864;    // 30720
  float* dtwT  = xpwTp + 30720;   // 4608
  float* opwT  = dtwT + 4608;     // 18432
  float* pmwT  = opwT + 18432;    // 73728  -> total ~239.8 MiB
  float* xdbl  = xpb;             // (B,L,160) 5,242,880 f (alias, conv-input dead after k2)
  float* outp  = xpb;             // out_pre alias (xdbl dead after k4c)

  k0_prep      <<<dim3(642),     dim3(256), 0, stream>>>(ipw,xpw,dtw,opw,pmrw, ipwT,xpwTp,dtwT,opwT,pmwT);
  k1_ln_inproj <<<dim3(64,3,8),  dim3(256), 0, stream>>>(x,lnw,lnb,ipwT, xT,xpb,zb);
  k2_conv      <<<dim3(1024,8),  dim3(192), 0, stream>>>(xpb,cw,cb, xcb);
  k3_proj      <<<dim3(128,8),   dim3(320), 0, stream>>>(xcb,xpwTp, xdbl);
  k4a_scanlocal<<<dim3(64,4,8),  dim3(192), 0, stream>>>(xdbl,xcb,alog,dtwT,dtb, lH,dT);
  k4b_chain    <<<dim3(384),     dim3(256), 0, stream>>>(lH,dT);
  k4c_scanfull <<<dim3(64,4,8),  dim3(192), 0, stream>>>(xdbl,xcb,alog,dtwT,dtb,lH,Dsv, yB);
  k5_combine   <<<dim3(64,8),    dim3(256), 0, stream>>>(yB,zb,xT,onw,onb,opwT, outp);
  k6_pm        <<<dim3(4,32,8),  dim3(192), 0, stream>>>(outp,pmnw,pmnb,pmwT, out);
}